// Round 1
// 166.580 us; speedup vs baseline: 1.0304x; 1.0304x over previous
//
#include <hip/hip_runtime.h>
#include <cstdint>
#include <cstddef>

// B=32 batch, K=4096 complex input pixels, N=4096 complex outputs.
// out[b,n] = sum_k (e_in[b,k]*ts[k]) * w[k,n]   (complex)
// Real-GEMM formulation, K'=8192 interleaved (re,im):
//   A[b][2k]=m_re, A[b][2k+1]=m_im
//   B_re[2k][n]=w_re, B_re[2k+1][n]=-w_im  -> out_re
//   B_im[2k][n]=w_im, B_im[2k+1][n]= w_re  -> out_im
// OUTPUT (established R5): float32 PLANAR — [re-plane 131072][im-plane 131072].
#define KC 4096
#define NN 4096
#define NB 32
#define HALF (NB * NN)

typedef __attribute__((ext_vector_type(8))) short  bf16x8;  // 8 bf16 (4 VGPRs)
typedef __attribute__((ext_vector_type(16))) float f32x16;  // 32x32 MFMA acc

__device__ __forceinline__ unsigned short f2bf(float f) {
    union { float f; unsigned u; } v; v.f = f;
    unsigned r = v.u + 0x7fffu + ((v.u >> 16) & 1u);
    return (unsigned short)(r >> 16);
}

// ---------------------------------------------------------------------------
// Kernel 1: modulated[b,k] = e_in[b,k] * (sigmoid(amp[k]) * exp(i*phase[k]))
// bf16 pairs in MFMA-A octet order: k'=2k+(re:0/im:1), octet o=k'>>3 (=k>>2),
// slot r=k'&7; dword index = ((k>>2)*32 + b)*4 + (k&3), re lo16 / im hi16.
// __sinf/__cosf/__expf: native-path transcendentals (no sincosf pointer-out
// slow path / scratch). Tolerance is absmax 1.0 — few-ulp error irrelevant.
// ---------------------------------------------------------------------------
__global__ __launch_bounds__(256) void prep_kernel(
    const float* __restrict__ in_re, const float* __restrict__ in_im,
    const float* __restrict__ amp,   const float* __restrict__ phase,
    uint32_t* __restrict__ wsA)
{
    int tid = blockIdx.x * 256 + threadIdx.x;   // 32*4096 threads
    int b = tid >> 12;
    int k = tid & (KC - 1);
    float er = in_re[tid], ei = in_im[tid];
    float a = amp[k], p = phase[k];
    float s = 1.0f / (1.0f + __expf(-a));
    float sn = __sinf(p);
    float cs = __cosf(p);
    float tr = s * cs, ti = s * sn;
    float mr = er * tr - ei * ti;
    float mi = er * ti + ei * tr;
    uint32_t pk = (uint32_t)f2bf(mr) | ((uint32_t)f2bf(mi) << 16);
    wsA[((((k >> 2) << 5) + b) << 2) | (k & 3)] = pk;
}

// ---------------------------------------------------------------------------
// Kernel 2: split-K complex GEMM via 2x mfma_f32_32x32x16_bf16 per step.
// Wave: 32 n-cols x all 32 batches. Lane: h=lane>>5 (K'-octet half),
// l32=lane&31 (m for A / n for B). Per step (8 complex k): 1 A-frag
// (global dwordx4 from wsA) + 8 coalesced W dwords -> pack B_re/B_im -> 2 MFMA.
// R6: 4-stage explicit register pipeline. Previous version had VGPR=40 ->
// compiler issued the 8 scalar W loads just-in-time -> ~900cy HBM latency
// fully exposed at 2 waves/SIMD (grid-limited). Holding 4 steps in named
// registers forces loads ~4 steps (>1000cy) ahead of use.
// ---------------------------------------------------------------------------
struct Stage {
    bf16x8 a;
    float r0, r1, r2, r3, i0, i1, i2, i3;
};

__device__ __forceinline__ void load_stage(
    Stage& s, const bf16x8* __restrict__ aptr,
    const float* __restrict__ pre, const float* __restrict__ pim, int t)
{
    s.a = aptr[(size_t)(2 * t) * 32];
    const float* pr = pre + (size_t)t * 8 * NN;
    const float* pi = pim + (size_t)t * 8 * NN;
    s.r0 = pr[0]; s.r1 = pr[NN]; s.r2 = pr[2 * NN]; s.r3 = pr[3 * NN];
    s.i0 = pi[0]; s.i1 = pi[NN]; s.i2 = pi[2 * NN]; s.i3 = pi[3 * NN];
}

__device__ __forceinline__ void compute_stage(
    const Stage& s, f32x16& accR, f32x16& accI)
{
    bf16x8 bR, bI;
    bR[0] = (short)f2bf(s.r0);  bR[1] = (short)f2bf(-s.i0);
    bR[2] = (short)f2bf(s.r1);  bR[3] = (short)f2bf(-s.i1);
    bR[4] = (short)f2bf(s.r2);  bR[5] = (short)f2bf(-s.i2);
    bR[6] = (short)f2bf(s.r3);  bR[7] = (short)f2bf(-s.i3);
    bI[0] = (short)f2bf(s.i0);  bI[1] = (short)f2bf(s.r0);
    bI[2] = (short)f2bf(s.i1);  bI[3] = (short)f2bf(s.r1);
    bI[4] = (short)f2bf(s.i2);  bI[5] = (short)f2bf(s.r2);
    bI[6] = (short)f2bf(s.i3);  bI[7] = (short)f2bf(s.r3);
    accR = __builtin_amdgcn_mfma_f32_32x32x16_bf16(s.a, bR, accR, 0, 0, 0);
    accI = __builtin_amdgcn_mfma_f32_32x32x16_bf16(s.a, bI, accI, 0, 0, 0);
}

__global__ __launch_bounds__(256) void gemm_kernel(
    const float* __restrict__ w_re, const float* __restrict__ w_im,
    const bf16x8* __restrict__ wsA, float2* __restrict__ wsP, int steps)
{
    const int lane = threadIdx.x & 63;
    const int wave = threadIdx.x >> 6;
    const int h    = lane >> 5;
    const int l32  = lane & 31;
    const int n    = blockIdx.x * 128 + wave * 32 + l32;
    const int s    = blockIdx.y;
    const int kbase = s * (steps * 8);   // complex-k base of this split

    f32x16 accR = {};
    f32x16 accI = {};

    const bf16x8* aptr = wsA + ((size_t)(kbase >> 2) + h) * 32 + l32;
    const float* pre = w_re + (size_t)(kbase + h * 4) * NN + n;
    const float* pim = w_im + (size_t)(kbase + h * 4) * NN + n;

    // steps = KC/S/8 is always a multiple of 4 (S is a power of two <= 16).
    Stage sA, sB, sC, sD;
    load_stage(sA, aptr, pre, pim, 0);
    load_stage(sB, aptr, pre, pim, 1);
    load_stage(sC, aptr, pre, pim, 2);
    load_stage(sD, aptr, pre, pim, 3);

    int t = 0;
    for (; t + 4 < steps; t += 4) {
        compute_stage(sA, accR, accI); load_stage(sA, aptr, pre, pim, t + 4);
        compute_stage(sB, accR, accI); load_stage(sB, aptr, pre, pim, t + 5);
        compute_stage(sC, accR, accI); load_stage(sC, aptr, pre, pim, t + 6);
        compute_stage(sD, accR, accI); load_stage(sD, aptr, pre, pim, t + 7);
    }
    compute_stage(sA, accR, accI);
    compute_stage(sB, accR, accI);
    compute_stage(sC, accR, accI);
    compute_stage(sD, accR, accI);

    // C/D layout (32x32, verified m74/m101): col = lane&31 (=n),
    // row(batch) = (reg&3) + 8*(reg>>2) + 4*h
#pragma unroll
    for (int r = 0; r < 16; ++r) {
        int brow = (r & 3) + 8 * (r >> 2) + 4 * h;
        float2 v; v.x = accR[r]; v.y = accI[r];
        wsP[((size_t)s * NB + brow) * NN + n] = v;
    }
}

// ---------------------------------------------------------------------------
// Kernel 3: planar output (proven R5): out[b*4096+n]=re, out[HALF+..]=im
// R6: float4 loads (2 complex per thread), unrolled.
// ---------------------------------------------------------------------------
__global__ __launch_bounds__(256) void reduce_kernel(
    const float4* __restrict__ wsP, float* __restrict__ out, int S)
{
    int tid = blockIdx.x * 256 + threadIdx.x;   // 65536 float4 = 2 complex
    float re0 = 0.f, im0 = 0.f, re1 = 0.f, im1 = 0.f;
#pragma unroll 4
    for (int s = 0; s < S; ++s) {
        float4 v = wsP[(size_t)s * (NB * NN / 2) + tid];
        re0 += v.x; im0 += v.y; re1 += v.z; im1 += v.w;
    }
    float2* o_re = (float2*)out + tid;
    float2* o_im = (float2*)(out + HALF) + tid;
    *o_re = make_float2(re0, re1);
    *o_im = make_float2(im0, im1);
}

extern "C" void kernel_launch(void* const* d_in, const int* in_sizes, int n_in,
                              void* d_out, int out_size, void* d_ws, size_t ws_size,
                              hipStream_t stream)
{
    const float* in_re  = (const float*)d_in[0];
    const float* in_im  = (const float*)d_in[1];
    const float* w_re   = (const float*)d_in[2];
    const float* w_im   = (const float*)d_in[3];
    const float* amp    = (const float*)d_in[4];
    const float* phase  = (const float*)d_in[5];

    const size_t A_BYTES = (size_t)1024 * 32 * 16;   // 512 KB bf16 A-fragments
    uint32_t* wsA = (uint32_t*)d_ws;
    float2*   wsP = (float2*)((char*)d_ws + A_BYTES);

    int S = 16;
    while (S > 1 && A_BYTES + (size_t)S * NB * NN * sizeof(float2) > ws_size) S >>= 1;
    int steps = (KC / S) / 8;

    prep_kernel<<<dim3((NB * KC) / 256), dim3(256), 0, stream>>>(
        in_re, in_im, amp, phase, wsA);

    gemm_kernel<<<dim3(NN / 128, S), dim3(256), 0, stream>>>(
        w_re, w_im, (const bf16x8*)wsA, wsP, steps);

    reduce_kernel<<<dim3((NB * NN / 2) / 256), dim3(256), 0, stream>>>(
        (const float4*)wsP, (float*)d_out, S);
}